// Round 8
// baseline (87.033 us; speedup 1.0000x reference)
//
#include <hip/hip_runtime.h>
#include <hip/hip_bf16.h>

#define BATCH 16
#define INCH 16
#define HH 64
#define WW 64
#define HO 62
#define WO 62
#define LTOT (HO * WO)      // 3844
#define OUTCH 128
#define KFULL 1296
#define NTRI 45
#define NSC 8               // super-chunks, 2 channels each
#define KPC 96              // padded K per super-chunk
#define TILE_N 124          // 2 output rows per block
#define NTILES 31
#define FROW 52             // dwords per Fl row (208 B)
#define NFRAG (2 * NSC * 3 * 4 * 64)  // 12288 16B A-fragments

typedef short bf16x8 __attribute__((ext_vector_type(8)));
typedef float f32x4 __attribute__((ext_vector_type(4)));

__device__ constexpr int TRI_A[NTRI] = {
  0,0,0,0,0,0,0,0,0, 1,1,1,1,1,1,1,1, 2,2,2,2,2,2,2,
  3,3,3,3,3,3, 4,4,4,4,4, 5,5,5,5, 6,6,6, 7,7, 8};
__device__ constexpr int TRI_B[NTRI] = {
  0,1,2,3,4,5,6,7,8, 1,2,3,4,5,6,7,8, 2,3,4,5,6,7,8,
  3,4,5,6,7,8, 4,5,6,7,8, 5,6,7,8, 6,7,8, 7,8, 8};

__device__ inline unsigned short f2bf(float x) {  // RNE
  unsigned int u = __float_as_uint(x);
  unsigned int r = ((u >> 16) & 1u) + 0x7FFFu;
  return (unsigned short)((u + r) >> 16);
}
__device__ inline unsigned int pack2(float lo, float hi) {
  __hip_bfloat162 h = __float22bfloat162_rn(make_float2(lo, hi));
  return *reinterpret_cast<unsigned int*>(&h);
}

// symmetrized W element: kl in [0,96), kl = half*48 + t (t>=45 -> 0)
__device__ inline float wsym_at(const float* __restrict__ W, int sc, int o, int kl) {
  int half = kl >= 48 ? 1 : 0;
  int t = kl - 48 * half;
  if (t >= NTRI) return 0.f;
  int a = TRI_A[t], b = TRI_B[t];
  int c = sc * 2 + half;
  float v = W[o * KFULL + c * 81 + a * 9 + b];
  if (a != b) v += W[o * KFULL + c * 81 + b * 9 + a];
  return v;
}

// Prep: A-fragments in MFMA lane order.
// frag idx = (((g*NSC+sc)*3+kc)*4+mf)*64 + lane; elem e: o=g*64+mf*16+(lane&15),
// k = kc*32+(lane>>4)*8+e
__global__ void prep_wfrag(const float* __restrict__ W, unsigned short* __restrict__ Wf) {
  int idx = blockIdx.x * 256 + threadIdx.x;
  if (idx >= NFRAG) return;
  int lane = idx & 63;
  int mf = (idx >> 6) & 3;
  int rest = idx >> 8;
  int kc = rest % 3;
  int scg = rest / 3;
  int sc = scg & 7, g = scg >> 3;
  int o = g * 64 + mf * 16 + (lane & 15);
  int k0 = kc * 32 + (lane >> 4) * 8;
  unsigned short v[8];
#pragma unroll
  for (int e = 0; e < 8; ++e) v[e] = f2bf(wsym_at(W, sc, o, k0 + e));
  uint4 pk;
  pk.x = (unsigned)v[0] | ((unsigned)v[1] << 16);
  pk.y = (unsigned)v[2] | ((unsigned)v[3] << 16);
  pk.z = (unsigned)v[4] | ((unsigned)v[5] << 16);
  pk.w = (unsigned)v[6] | ((unsigned)v[7] << 16);
  *(uint4*)&Wf[(size_t)idx * 8] = pk;
}

template <bool USE_WS>
__global__ __launch_bounds__(256, 2) void conv2o_ping(
    const float* __restrict__ X, const float* __restrict__ Wraw,
    const uint4* __restrict__ Wf, float* __restrict__ Out) {
  __shared__ float xs[INCH][4][64];            // 16 KB, staged once
  __shared__ unsigned int Fl[2][128 * FROW];   // 2 x 26 KB, double-buffered

  const int tid = threadIdx.x;
  const int blk = blockIdx.x;
  const int b = blk / NTILES;
  const int tile = blk % NTILES;
  const int y0 = tile * 2;
  const int l0 = tile * TILE_N;

  const int lane = tid & 63;
  const int wave = tid >> 6;
  const int g = wave >> 1;             // m-group (o-half)
  const int mbase = g * 64;
  const int nbase = (wave & 1) * 64;
  const int lr = lane & 15;
  const int lh = lane >> 4;

  // ---- stage all x: 1024 float4 over 256 threads ----
#pragma unroll
  for (int t = 0; t < 4; ++t) {
    int i = tid + t * 256;
    int chr = i >> 4, seg = i & 15;
    int ch = chr >> 2, r = chr & 3;
    *(float4*)&xs[ch][r][seg * 4] =
        *(const float4*)&X[((size_t)(b * INCH + ch) * HH + (y0 + r)) * WW + seg * 4];
  }

  const int q = tid & 127;
  const int half = tid >> 7;
  const int qrow = q / 62;
  const int qcol = q - qrow * 62;

  // F-compute: products for (pos q, channel scn*2+half) -> Fl[buf] (buf literal)
  auto computeF = [&](int scn, int buf) {
    const unsigned base = q * FROW + half * 24;
    if (q < TILE_N) {
      const int ch = scn * 2 + half;
      float p[9];
#pragma unroll
      for (int di = 0; di < 3; ++di)
#pragma unroll
        for (int dj = 0; dj < 3; ++dj)
          p[di * 3 + dj] = xs[ch][qrow + di][qcol + dj];
#pragma unroll
      for (int j = 0; j < 6; ++j) {
        unsigned int d[4];
#pragma unroll
        for (int w = 0; w < 4; ++w) {
          const int m = 4 * j + w;
          float lo = (2 * m < NTRI) ? p[TRI_A[2 * m]] * p[TRI_B[2 * m]] : 0.f;
          float hi = (2 * m + 1 < NTRI) ? p[TRI_A[2 * m + 1]] * p[TRI_B[2 * m + 1]] : 0.f;
          d[w] = pack2(lo, hi);
        }
        *(uint4*)&Fl[buf][base + j * 4] = make_uint4(d[0], d[1], d[2], d[3]);
      }
    } else {
      const uint4 z = make_uint4(0u, 0u, 0u, 0u);
#pragma unroll
      for (int j = 0; j < 6; ++j) *(uint4*)&Fl[buf][base + j * 4] = z;
    }
  };

  // A-fragment load (12 x uint4 for super-chunk sc) into a NAMED array
  auto loadA = [&](uint4* ap, int sc) {
    if (USE_WS) {
      const uint4* basep = Wf + (size_t)((g * NSC + sc) * 3) * 4 * 64;
#pragma unroll
      for (int f = 0; f < 12; ++f) ap[f] = basep[f * 64 + lane];
    } else {
#pragma unroll
      for (int kc = 0; kc < 3; ++kc)
#pragma unroll
        for (int mf = 0; mf < 4; ++mf) {
          const int o = mbase + mf * 16 + lr;
          const int k0 = kc * 32 + lh * 8;
          unsigned short v[8];
#pragma unroll
          for (int e = 0; e < 8; ++e) v[e] = f2bf(wsym_at(Wraw, sc, o, k0 + e));
          uint4 pk;
          pk.x = (unsigned)v[0] | ((unsigned)v[1] << 16);
          pk.y = (unsigned)v[2] | ((unsigned)v[3] << 16);
          pk.z = (unsigned)v[4] | ((unsigned)v[5] << 16);
          pk.w = (unsigned)v[6] | ((unsigned)v[7] << 16);
          ap[kc * 4 + mf] = pk;
        }
    }
  };

  f32x4 acc[4][4];
#pragma unroll
  for (int mf = 0; mf < 4; ++mf)
#pragma unroll
    for (int nf = 0; nf < 4; ++nf) acc[mf][nf] = (f32x4){0.f, 0.f, 0.f, 0.f};

  // MFMA over 3 k-chunks from named A-array + Fl[buf] (buf literal)
  auto mfmaStep = [&](const uint4* ap, int buf) {
#pragma unroll
    for (int kc = 0; kc < 3; ++kc) {
      const int koff = kc * 16 + lh * 4;
      bf16x8 bfr[4];
#pragma unroll
      for (int nf = 0; nf < 4; ++nf)
        bfr[nf] = *(const bf16x8*)&Fl[buf][(nbase + nf * 16 + lr) * FROW + koff];
#pragma unroll
      for (int mf = 0; mf < 4; ++mf) {
        const bf16x8 af = __builtin_bit_cast(bf16x8, ap[kc * 4 + mf]);
#pragma unroll
        for (int nf = 0; nf < 4; ++nf)
          acc[mf][nf] = __builtin_amdgcn_mfma_f32_16x16x32_bf16(af, bfr[nf], acc[mf][nf], 0, 0, 0);
      }
    }
  };

  __syncthreads();  // xs ready

  uint4 apfA[12], apfB[12];
  loadA(apfA, 0);
  computeF(0, 0);
  __syncthreads();  // F(0) ready

  // Ping-pong: unroll 1 keeps body small, apfA/apfB statically named (no spill)
#pragma unroll 1
  for (int it = 0; it < 4; ++it) {
    const int sc = 2 * it;
    // even step: consume {apfA, Fl[0]}, prefetch {apfB <- W(sc+1), Fl[1] <- F(sc+1)}
    loadA(apfB, sc + 1);
    computeF(sc + 1, 1);
    mfmaStep(apfA, 0);
    __syncthreads();
    // odd step: consume {apfB, Fl[1]}, prefetch {apfA <- W(sc+2), Fl[0] <- F(sc+2)}
    if (it < 3) {
      loadA(apfA, sc + 2);
      computeF(sc + 2, 0);
    }
    mfmaStep(apfB, 1);
    __syncthreads();
  }

  // ---- epilogue (layout verified in R3): D col=pos(lr), row=o(lh*4+r) ----
#pragma unroll
  for (int nf = 0; nf < 4; ++nf) {
    const int pos = nbase + nf * 16 + lr;
    if (pos < TILE_N) {
      const int l = l0 + pos;
#pragma unroll
      for (int mf = 0; mf < 4; ++mf) {
        const int o = mbase + mf * 16 + lh * 4;
        float* outp = &Out[((size_t)(b * OUTCH + o)) * LTOT + l];
#pragma unroll
        for (int r = 0; r < 4; ++r) outp[(size_t)r * LTOT] = acc[mf][nf][r];
      }
    }
  }
}

extern "C" void kernel_launch(void* const* d_in, const int* in_sizes, int n_in,
                              void* d_out, int out_size, void* d_ws, size_t ws_size,
                              hipStream_t stream) {
  const float* X = (const float*)d_in[0];
  const float* W = (const float*)d_in[1];
  float* Out = (float*)d_out;

  const size_t wf_bytes = (size_t)NFRAG * 16;  // 196608 B
  const int use_ws = (ws_size >= wf_bytes) ? 1 : 0;

  if (use_ws) {
    prep_wfrag<<<(NFRAG + 255) / 256, 256, 0, stream>>>(W, (unsigned short*)d_ws);
    conv2o_ping<true><<<BATCH * NTILES, 256, 0, stream>>>(X, W, (const uint4*)d_ws, Out);
  } else {
    conv2o_ping<false><<<BATCH * NTILES, 256, 0, stream>>>(X, W, (const uint4*)d_ws, Out);
  }
}

// Round 9
// 86.805 us; speedup vs baseline: 1.0026x; 1.0026x over previous
//
#include <hip/hip_runtime.h>
#include <hip/hip_bf16.h>

#define BATCH 16
#define INCH 16
#define HH 64
#define WW 64
#define HO 62
#define WO 62
#define LTOT (HO * WO)      // 3844
#define OUTCH 128
#define KFULL 1296
#define NTRI 45
#define NSC 8               // super-chunks, 2 channels each
#define TILE_N 124          // 2 output rows per block
#define NTILES 31
#define FROW 52             // dwords per Fl row (208 B)
#define NFRAG (2 * NSC * 3 * 4 * 64)  // 12288 16B A-fragments

typedef short bf16x8 __attribute__((ext_vector_type(8)));
typedef float f32x4 __attribute__((ext_vector_type(4)));

__device__ constexpr int TRI_A[NTRI] = {
  0,0,0,0,0,0,0,0,0, 1,1,1,1,1,1,1,1, 2,2,2,2,2,2,2,
  3,3,3,3,3,3, 4,4,4,4,4, 5,5,5,5, 6,6,6, 7,7, 8};
__device__ constexpr int TRI_B[NTRI] = {
  0,1,2,3,4,5,6,7,8, 1,2,3,4,5,6,7,8, 2,3,4,5,6,7,8,
  3,4,5,6,7,8, 4,5,6,7,8, 5,6,7,8, 6,7,8, 7,8, 8};

__device__ inline unsigned short f2bf(float x) {  // RNE
  unsigned int u = __float_as_uint(x);
  unsigned int r = ((u >> 16) & 1u) + 0x7FFFu;
  return (unsigned short)((u + r) >> 16);
}
__device__ inline unsigned int pack2(float lo, float hi) {
  __hip_bfloat162 h = __float22bfloat162_rn(make_float2(lo, hi));
  return *reinterpret_cast<unsigned int*>(&h);
}

// symmetrized W element: kl in [0,96), kl = half*48 + t (t>=45 -> 0)
__device__ inline float wsym_at(const float* __restrict__ W, int sc, int o, int kl) {
  int half = kl >= 48 ? 1 : 0;
  int t = kl - 48 * half;
  if (t >= NTRI) return 0.f;
  int a = TRI_A[t], b = TRI_B[t];
  int c = sc * 2 + half;
  float v = W[o * KFULL + c * 81 + a * 9 + b];
  if (a != b) v += W[o * KFULL + c * 81 + b * 9 + a];
  return v;
}

// Prep: A-fragments in MFMA lane order.
// frag idx = (((g*NSC+sc)*3+kc)*4+mf)*64 + lane; elem e: o=g*64+mf*16+(lane&15),
// k = kc*32+(lane>>4)*8+e
__global__ void prep_wfrag(const float* __restrict__ W, unsigned short* __restrict__ Wf) {
  int idx = blockIdx.x * 256 + threadIdx.x;
  if (idx >= NFRAG) return;
  int lane = idx & 63;
  int mf = (idx >> 6) & 3;
  int rest = idx >> 8;
  int kc = rest % 3;
  int scg = rest / 3;
  int sc = scg & 7, g = scg >> 3;
  int o = g * 64 + mf * 16 + (lane & 15);
  int k0 = kc * 32 + (lane >> 4) * 8;
  unsigned short v[8];
#pragma unroll
  for (int e = 0; e < 8; ++e) v[e] = f2bf(wsym_at(W, sc, o, k0 + e));
  uint4 pk;
  pk.x = (unsigned)v[0] | ((unsigned)v[1] << 16);
  pk.y = (unsigned)v[2] | ((unsigned)v[3] << 16);
  pk.z = (unsigned)v[4] | ((unsigned)v[5] << 16);
  pk.w = (unsigned)v[6] | ((unsigned)v[7] << 16);
  *(uint4*)&Wf[(size_t)idx * 8] = pk;
}

template <bool USE_WS>
__global__ __launch_bounds__(256, 3) void conv2o_occ3(
    const float* __restrict__ X, const float* __restrict__ Wraw,
    const uint4* __restrict__ Wf, float* __restrict__ Out) {
  __shared__ float xs[INCH][4][64];        // 16 KB, staged once
  __shared__ unsigned int Fl[128 * FROW];  // 26.6 KB, single buffer

  const int tid = threadIdx.x;
  const int blk = blockIdx.x;
  const int b = blk / NTILES;
  const int tile = blk % NTILES;
  const int y0 = tile * 2;
  const int l0 = tile * TILE_N;

  const int lane = tid & 63;
  const int wave = tid >> 6;          // 4 waves
  const int g = wave >> 1;            // m-group (o-half), 0..1
  const int mbase = g * 64;
  const int nbase = (wave & 1) * 64;
  const int lr = lane & 15;
  const int lh = lane >> 4;

  // ---- stage all x: 1024 float4 over 256 threads ----
#pragma unroll
  for (int t = 0; t < 4; ++t) {
    int i = tid + t * 256;
    int chr = i >> 4, seg = i & 15;
    int ch = chr >> 2, r = chr & 3;
    *(float4*)&xs[ch][r][seg * 4] =
        *(const float4*)&X[((size_t)(b * INCH + ch) * HH + (y0 + r)) * WW + seg * 4];
  }

  const int q = tid & 127;
  const int half = tid >> 7;
  const int qrow = q / 62;
  const int qcol = q - qrow * 62;
  const int xorw = ((q >> 3) & 3) << 2;   // write-side swizzle for row q

  // F-compute: products for (pos q, channel scn*2+half) -> Fl (swizzled cols)
  auto computeF = [&](int scn) {
    const unsigned base = q * FROW;
    if (q < TILE_N) {
      const int ch = scn * 2 + half;
      float p[9];
#pragma unroll
      for (int di = 0; di < 3; ++di)
#pragma unroll
        for (int dj = 0; dj < 3; ++dj)
          p[di * 3 + dj] = xs[ch][qrow + di][qcol + dj];
#pragma unroll
      for (int j = 0; j < 6; ++j) {
        unsigned int d[4];
#pragma unroll
        for (int w = 0; w < 4; ++w) {
          const int m = 4 * j + w;
          float lo = (2 * m < NTRI) ? p[TRI_A[2 * m]] * p[TRI_B[2 * m]] : 0.f;
          float hi = (2 * m + 1 < NTRI) ? p[TRI_A[2 * m + 1]] * p[TRI_B[2 * m + 1]] : 0.f;
          d[w] = pack2(lo, hi);
        }
        const int col = (half * 24 + j * 4) ^ xorw;
        *(uint4*)&Fl[base + col] = make_uint4(d[0], d[1], d[2], d[3]);
      }
    } else {
      const uint4 z = make_uint4(0u, 0u, 0u, 0u);
#pragma unroll
      for (int j = 0; j < 6; ++j) {
        const int col = (half * 24 + j * 4) ^ xorw;
        *(uint4*)&Fl[base + col] = z;
      }
    }
  };

  // A-fragment load (12 x uint4 for super-chunk sc)
  auto loadA = [&](uint4* ap, int sc) {
    if (USE_WS) {
      const uint4* basep = Wf + (size_t)((g * NSC + sc) * 3) * 4 * 64;
#pragma unroll
      for (int f = 0; f < 12; ++f) ap[f] = basep[f * 64 + lane];
    } else {
#pragma unroll
      for (int kc = 0; kc < 3; ++kc)
#pragma unroll
        for (int mf = 0; mf < 4; ++mf) {
          const int o = mbase + mf * 16 + lr;
          const int k0 = kc * 32 + lh * 8;
          unsigned short v[8];
#pragma unroll
          for (int e = 0; e < 8; ++e) v[e] = f2bf(wsym_at(Wraw, sc, o, k0 + e));
          uint4 pk;
          pk.x = (unsigned)v[0] | ((unsigned)v[1] << 16);
          pk.y = (unsigned)v[2] | ((unsigned)v[3] << 16);
          pk.z = (unsigned)v[4] | ((unsigned)v[5] << 16);
          pk.w = (unsigned)v[6] | ((unsigned)v[7] << 16);
          ap[kc * 4 + mf] = pk;
        }
    }
  };

  f32x4 acc[4][4];
#pragma unroll
  for (int mf = 0; mf < 4; ++mf)
#pragma unroll
    for (int nf = 0; nf < 4; ++nf) acc[mf][nf] = (f32x4){0.f, 0.f, 0.f, 0.f};

  // MFMA over 3 k-chunks; Fl reads use the matching row swizzle
  auto mfmaStep = [&](const uint4* ap) {
#pragma unroll
    for (int kc = 0; kc < 3; ++kc) {
      const int koff = kc * 16 + lh * 4;
      bf16x8 bfr[4];
#pragma unroll
      for (int nf = 0; nf < 4; ++nf) {
        const int row = nbase + nf * 16 + lr;
        const int col = koff ^ (((row >> 3) & 3) << 2);
        bfr[nf] = *(const bf16x8*)&Fl[row * FROW + col];
      }
#pragma unroll
      for (int mf = 0; mf < 4; ++mf) {
        const bf16x8 af = __builtin_bit_cast(bf16x8, ap[kc * 4 + mf]);
#pragma unroll
        for (int nf = 0; nf < 4; ++nf)
          acc[mf][nf] = __builtin_amdgcn_mfma_f32_16x16x32_bf16(af, bfr[nf], acc[mf][nf], 0, 0, 0);
      }
    }
  };

  uint4 apf[12];
  loadA(apf, 0);      // no xs dependency; lands while xs barrier settles
  __syncthreads();    // xs ready

#pragma unroll 1
  for (int sc = 0; sc < NSC; ++sc) {
    computeF(sc);               // xs -> VALU -> Fl
    __syncthreads();            // Fl ready
    mfmaStep(apf);              // reads Fl + apf
    if (sc + 1 < NSC) {
      loadA(apf, sc + 1);       // WAR after mfma; lands during barrier+computeF
      __syncthreads();          // Fl consumed; next computeF may overwrite
    }
  }

  // ---- epilogue (layout verified in R3): D col=pos(lr), row=o(lh*4+r) ----
#pragma unroll
  for (int nf = 0; nf < 4; ++nf) {
    const int pos = nbase + nf * 16 + lr;
    if (pos < TILE_N) {
      const int l = l0 + pos;
#pragma unroll
      for (int mf = 0; mf < 4; ++mf) {
        const int o = mbase + mf * 16 + lh * 4;
        float* outp = &Out[((size_t)(b * OUTCH + o)) * LTOT + l];
#pragma unroll
        for (int r = 0; r < 4; ++r) outp[(size_t)r * LTOT] = acc[mf][nf][r];
      }
    }
  }
}

extern "C" void kernel_launch(void* const* d_in, const int* in_sizes, int n_in,
                              void* d_out, int out_size, void* d_ws, size_t ws_size,
                              hipStream_t stream) {
  const float* X = (const float*)d_in[0];
  const float* W = (const float*)d_in[1];
  float* Out = (float*)d_out;

  const size_t wf_bytes = (size_t)NFRAG * 16;  // 196608 B
  const int use_ws = (ws_size >= wf_bytes) ? 1 : 0;

  if (use_ws) {
    prep_wfrag<<<(NFRAG + 255) / 256, 256, 0, stream>>>(W, (unsigned short*)d_ws);
    conv2o_occ3<true><<<BATCH * NTILES, 256, 0, stream>>>(X, W, (const uint4*)d_ws, Out);
  } else {
    conv2o_occ3<false><<<BATCH * NTILES, 256, 0, stream>>>(X, W, (const uint4*)d_ws, Out);
  }
}

// Round 12
// 86.575 us; speedup vs baseline: 1.0053x; 1.0027x over previous
//
#include <hip/hip_runtime.h>
#include <hip/hip_bf16.h>

#define BATCH 16
#define INCH 16
#define HH 64
#define WW 64
#define HO 62
#define WO 62
#define LTOT (HO * WO)      // 3844
#define OUTCH 128
#define KFULL 1296
#define NTRI 45
#define NSC 8               // super-chunks, 2 channels each
#define TILE 62             // one output row per block
#define FROW 52             // dwords per Fl row (208 B)
#define NFRAG (2 * NSC * 3 * 4 * 64)  // 12288 16B A-fragments

typedef short bf16x8 __attribute__((ext_vector_type(8)));
typedef float f32x4 __attribute__((ext_vector_type(4)));

__device__ constexpr int TRI_A[NTRI] = {
  0,0,0,0,0,0,0,0,0, 1,1,1,1,1,1,1,1, 2,2,2,2,2,2,2,
  3,3,3,3,3,3, 4,4,4,4,4, 5,5,5,5, 6,6,6, 7,7, 8};
__device__ constexpr int TRI_B[NTRI] = {
  0,1,2,3,4,5,6,7,8, 1,2,3,4,5,6,7,8, 2,3,4,5,6,7,8,
  3,4,5,6,7,8, 4,5,6,7,8, 5,6,7,8, 6,7,8, 7,8, 8};

__device__ inline unsigned short f2bf(float x) {  // RNE
  unsigned int u = __float_as_uint(x);
  unsigned int r = ((u >> 16) & 1u) + 0x7FFFu;
  return (unsigned short)((u + r) >> 16);
}
__device__ inline unsigned int pack2(float lo, float hi) {
  __hip_bfloat162 h = __float22bfloat162_rn(make_float2(lo, hi));
  return *reinterpret_cast<unsigned int*>(&h);
}

// symmetrized W element: kl in [0,96), kl = half*48 + t (t>=45 -> 0)
__device__ inline float wsym_at(const float* __restrict__ W, int sc, int o, int kl) {
  int half = kl >= 48 ? 1 : 0;
  int t = kl - 48 * half;
  if (t >= NTRI) return 0.f;
  int a = TRI_A[t], b = TRI_B[t];
  int c = sc * 2 + half;
  float v = W[o * KFULL + c * 81 + a * 9 + b];
  if (a != b) v += W[o * KFULL + c * 81 + b * 9 + a];
  return v;
}

// Prep: A-fragments in MFMA lane order (unchanged layout, verified R3-R9).
// frag idx = (((g*NSC+sc)*3+kc)*4+mf)*64 + lane; elem e: o=g*64+mf*16+(lane&15),
// k = kc*32+(lane>>4)*8+e
__global__ void prep_wfrag(const float* __restrict__ W, unsigned short* __restrict__ Wf) {
  int idx = blockIdx.x * 256 + threadIdx.x;
  if (idx >= NFRAG) return;
  int lane = idx & 63;
  int mf = (idx >> 6) & 3;
  int rest = idx >> 8;
  int kc = rest % 3;
  int scg = rest / 3;
  int sc = scg & 7, g = scg >> 3;
  int o = g * 64 + mf * 16 + (lane & 15);
  int k0 = kc * 32 + (lane >> 4) * 8;
  unsigned short v[8];
#pragma unroll
  for (int e = 0; e < 8; ++e) v[e] = f2bf(wsym_at(W, sc, o, k0 + e));
  uint4 pk;
  pk.x = (unsigned)v[0] | ((unsigned)v[1] << 16);
  pk.y = (unsigned)v[2] | ((unsigned)v[3] << 16);
  pk.z = (unsigned)v[4] | ((unsigned)v[5] << 16);
  pk.w = (unsigned)v[6] | ((unsigned)v[7] << 16);
  *(uint4*)&Wf[(size_t)idx * 8] = pk;
}

// Row-blocks: 992 blocks (b, y), 128 threads = 2 waves.
// wave = g (o-half). Per wave: 4 mf x 4 nf accumulators over TILE=62 (+2 pad).
template <bool USE_WS>
__global__ __launch_bounds__(128, 2) void conv2o_row(
    const float* __restrict__ X, const float* __restrict__ Wraw,
    const uint4* __restrict__ Wf, float* __restrict__ Out) {
  __shared__ float xs[INCH][3][64];         // 12 KB, staged once (rows y..y+2)
  __shared__ unsigned int Fl[2][64 * FROW]; // 2 x 13.3 KB, double-buffered

  const int tid = threadIdx.x;
  const int blk = blockIdx.x;
  const int b = blk / HO;
  const int y = blk % HO;
  const int l0 = y * WO;

  const int lane = tid & 63;
  const int g = tid >> 6;             // wave index = m-group (o-half)
  const int mbase = g * 64;
  const int lr = lane & 15;
  const int lh = lane >> 4;

  // ---- stage xs: 3 rows x 16 ch x 64 cols = 768 float4, 6 per thread ----
#pragma unroll
  for (int t = 0; t < 6; ++t) {
    int i = tid + t * 128;
    int ch = i / 48;
    int rem = i % 48;
    int r = rem / 16, seg = rem % 16;
    *(float4*)&xs[ch][r][seg * 4] =
        *(const float4*)&X[((size_t)(b * INCH + ch) * HH + (y + r)) * WW + seg * 4];
  }

  const int q = tid & 63;             // position (col); 62,63 are pad
  const int half = tid >> 6;          // channel within sc (== g, roles orthogonal)
  const int xorw = ((q >> 3) & 3) << 2;

  // F-compute: 45 products for (pos q, ch scn*2+half) -> Fl[buf], swizzled cols
  auto computeF = [&](int scn, int buf) {
    const unsigned base = (unsigned)q * FROW;
    if (q < TILE) {
      const int ch = scn * 2 + half;
      float p[9];
#pragma unroll
      for (int di = 0; di < 3; ++di)
#pragma unroll
        for (int dj = 0; dj < 3; ++dj)
          p[di * 3 + dj] = xs[ch][di][q + dj];
#pragma unroll
      for (int j = 0; j < 6; ++j) {
        unsigned int d[4];
#pragma unroll
        for (int w = 0; w < 4; ++w) {
          const int m = 4 * j + w;
          float lo = (2 * m < NTRI) ? p[TRI_A[2 * m]] * p[TRI_B[2 * m]] : 0.f;
          float hi = (2 * m + 1 < NTRI) ? p[TRI_A[2 * m + 1]] * p[TRI_B[2 * m + 1]] : 0.f;
          d[w] = pack2(lo, hi);
        }
        const int col = (half * 24 + j * 4) ^ xorw;
        *(uint4*)&Fl[buf][base + col] = make_uint4(d[0], d[1], d[2], d[3]);
      }
    } else {
      const uint4 z = make_uint4(0u, 0u, 0u, 0u);
#pragma unroll
      for (int j = 0; j < 6; ++j) {
        const int col = (half * 24 + j * 4) ^ xorw;
        *(uint4*)&Fl[buf][base + col] = z;
      }
    }
  };

  // A-fragment load (12 x uint4 for super-chunk sc, this wave's g)
  auto loadA = [&](uint4* ap, int sc) {
    if (USE_WS) {
      const uint4* basep = Wf + (size_t)((g * NSC + sc) * 3) * 4 * 64;
#pragma unroll
      for (int f = 0; f < 12; ++f) ap[f] = basep[f * 64 + lane];
    } else {
#pragma unroll
      for (int kc = 0; kc < 3; ++kc)
#pragma unroll
        for (int mf = 0; mf < 4; ++mf) {
          const int o = mbase + mf * 16 + lr;
          const int k0 = kc * 32 + lh * 8;
          unsigned short v[8];
#pragma unroll
          for (int e = 0; e < 8; ++e) v[e] = f2bf(wsym_at(Wraw, sc, o, k0 + e));
          uint4 pk;
          pk.x = (unsigned)v[0] | ((unsigned)v[1] << 16);
          pk.y = (unsigned)v[2] | ((unsigned)v[3] << 16);
          pk.z = (unsigned)v[4] | ((unsigned)v[5] << 16);
          pk.w = (unsigned)v[6] | ((unsigned)v[7] << 16);
          ap[kc * 4 + mf] = pk;
        }
    }
  };

  f32x4 acc[4][4];
#pragma unroll
  for (int mf = 0; mf < 4; ++mf)
#pragma unroll
    for (int nf = 0; nf < 4; ++nf) acc[mf][nf] = (f32x4){0.f, 0.f, 0.f, 0.f};

  // MFMA over 3 k-chunks; Fl reads use matching row swizzle
  auto mfmaStep = [&](const uint4* ap, int buf) {
#pragma unroll
    for (int kc = 0; kc < 3; ++kc) {
      const int koff = kc * 16 + lh * 4;
      bf16x8 bfr[4];
#pragma unroll
      for (int nf = 0; nf < 4; ++nf) {
        const int row = nf * 16 + lr;
        const int col = koff ^ (((row >> 3) & 3) << 2);
        bfr[nf] = *(const bf16x8*)&Fl[buf][row * FROW + col];
      }
#pragma unroll
      for (int mf = 0; mf < 4; ++mf) {
        const bf16x8 af = __builtin_bit_cast(bf16x8, ap[kc * 4 + mf]);
#pragma unroll
        for (int nf = 0; nf < 4; ++nf)
          acc[mf][nf] = __builtin_amdgcn_mfma_f32_16x16x32_bf16(af, bfr[nf], acc[mf][nf], 0, 0, 0);
      }
    }
  };

  uint4 apfA[12], apfB[12];
  loadA(apfA, 0);
  __syncthreads();    // xs ready
  computeF(0, 0);
  __syncthreads();    // F(0) ready

  // 2-step ping-pong, ONE barrier per sc. A-loads issued ~2 phases before use.
#pragma unroll 1
  for (int it = 0; it < 4; ++it) {
    const int sc = 2 * it;
    loadA(apfB, sc + 1);          // early issue; lands during computeF+mfma
    computeF(sc + 1, 1);
    mfmaStep(apfA, 0);            // consume sc
    __syncthreads();              // F(sc+1) ready; Fl[0] free
    if (it < 3) {
      loadA(apfA, sc + 2);
      computeF(sc + 2, 0);
    }
    mfmaStep(apfB, 1);            // consume sc+1
    __syncthreads();              // F(sc+2) ready; Fl[1] free
  }

  // ---- epilogue (layout verified R3): D col=pos(lr), row=o(lh*4+r) ----
#pragma unroll
  for (int nf = 0; nf < 4; ++nf) {
    const int pos = nf * 16 + lr;
    if (pos < TILE) {
      const int l = l0 + pos;
#pragma unroll
      for (int mf = 0; mf < 4; ++mf) {
        const int o = mbase + mf * 16 + lh * 4;
        float* outp = &Out[((size_t)(b * OUTCH + o)) * LTOT + l];
#pragma unroll
        for (int r = 0; r < 4; ++r) outp[(size_t)r * LTOT] = acc[mf][nf][r];
      }
    }
  }
}

extern "C" void kernel_launch(void* const* d_in, const int* in_sizes, int n_in,
                              void* d_out, int out_size, void* d_ws, size_t ws_size,
                              hipStream_t stream) {
  const float* X = (const float*)d_in[0];
  const float* W = (const float*)d_in[1];
  float* Out = (float*)d_out;

  const size_t wf_bytes = (size_t)NFRAG * 16;  // 196608 B
  const int use_ws = (ws_size >= wf_bytes) ? 1 : 0;

  if (use_ws) {
    prep_wfrag<<<(NFRAG + 255) / 256, 256, 0, stream>>>(W, (unsigned short*)d_ws);
    conv2o_row<true><<<BATCH * HO, 128, 0, stream>>>(X, W, (const uint4*)d_ws, Out);
  } else {
    conv2o_row<false><<<BATCH * HO, 128, 0, stream>>>(X, W, (const uint4*)d_ws, Out);
  }
}